// Round 1
// baseline (4539.792 us; speedup 1.0000x reference)
//
#include <hip/hip_runtime.h>

#define N_NODES 6272
#define CDIM    2048
#define ODIM    512
#define KNN     8

#define TM   64
#define TN   128
#define CKG  32
#define NCOLT (N_NODES / TN)   // 49
#define NPANEL (N_NODES / TM)  // 98

// ---------------- workspace layout (bytes) ----------------
#define SQ_OFF     0u
#define CANDV_OFF  (SQ_OFF    + N_NODES*4u)                 // 25088
#define CANDI_OFF  (CANDV_OFF + N_NODES*32u*4u)             // + 802816
#define KNN_OFF    (CANDI_OFF + N_NODES*32u*4u)
#define DEG_OFF    (KNN_OFF   + N_NODES*8u*4u)
#define CNT_OFF    (DEG_OFF   + N_NODES*4u)
#define DINV_OFF   (CNT_OFF   + N_NODES*4u)
#define RPTR_OFF   (DINV_OFF  + N_NODES*4u)
#define COL_OFF    (RPTR_OFF  + ((N_NODES+1)*4u + 255u & ~255u))
#define HW_OFF     (COL_OFF   + (9u*N_NODES*4u + 255u & ~255u))
#define H1_OFF     (HW_OFF    + N_NODES*ODIM*4u)

// ---------------- sq[i] = sum_c x[i][c]^2 ----------------
__global__ __launch_bounds__(64) void sq_kernel(const float* __restrict__ x,
                                                float* __restrict__ sq) {
    int i = blockIdx.x;
    int t = threadIdx.x;
    const float* row = x + (size_t)i * CDIM;
    float s = 0.f;
#pragma unroll
    for (int k = 0; k < CDIM / 256; k++) {
        float4 v = *(const float4*)(row + (k * 64 + t) * 4);
        s += v.x * v.x + v.y * v.y + v.z * v.z + v.w * v.w;
    }
#pragma unroll
    for (int off = 32; off; off >>= 1) s += __shfl_down(s, off, 64);
    if (t == 0) sq[i] = s;
}

// ------------- fused Gram tile + per-row running top-8 -------------
// grid = NPANEL*4; block handles rows [panel*64, +64), col tiles t = q,q+4,...
__global__ __launch_bounds__(256) void gram_topk_kernel(
        const float* __restrict__ x, const float* __restrict__ sq,
        float* __restrict__ candv, int* __restrict__ candi) {
    __shared__ float A_lds[CKG][TM];      // [c][row]
    __shared__ float B_lds[CKG][TN];      // [c][col]
    __shared__ float S[TM][TN + 1];       // +1 pad: conflict-free row scans
    __shared__ float topv[TM][9];         // 9-pad for bank spread
    __shared__ int   topi[TM][9];

    int tid   = threadIdx.x;
    int panel = blockIdx.x >> 2;
    int q     = blockIdx.x & 3;
    int i0    = panel * TM;
    int ty = tid >> 4, tx = tid & 15;

    if (tid < TM) {
#pragma unroll
        for (int k = 0; k < 8; k++) { topv[tid][k] = 3.4e38f; topi[tid][k] = 0x7fffffff; }
    }

    float sqi[4];
#pragma unroll
    for (int rr = 0; rr < 4; rr++) sqi[rr] = sq[i0 + ty * 4 + rr];

    for (int t = q; t < NCOLT; t += 4) {
        int j0 = t * TN;
        float acc[4][8];
#pragma unroll
        for (int a = 0; a < 4; a++)
#pragma unroll
            for (int b = 0; b < 8; b++) acc[a][b] = 0.f;

        for (int cc = 0; cc < CDIM; cc += CKG) {
            __syncthreads();   // protect LDS from readers of previous chunk / scanners
            {   // A tile: 64 rows x 32 c, transposed into [c][row]
                int r  = tid >> 2;
                int cg = (tid & 3) * 8;
                const float* src = x + (size_t)(i0 + r) * CDIM + cc + cg;
                float4 a0 = *(const float4*)src;
                float4 a1 = *(const float4*)(src + 4);
                A_lds[cg + 0][r] = a0.x; A_lds[cg + 1][r] = a0.y;
                A_lds[cg + 2][r] = a0.z; A_lds[cg + 3][r] = a0.w;
                A_lds[cg + 4][r] = a1.x; A_lds[cg + 5][r] = a1.y;
                A_lds[cg + 6][r] = a1.z; A_lds[cg + 7][r] = a1.w;
            }
            {   // B tile: 128 rows x 32 c, transposed into [c][col]
                int r  = tid >> 1;
                int cg = (tid & 1) * 16;
                const float* src = x + (size_t)(j0 + r) * CDIM + cc + cg;
#pragma unroll
                for (int u = 0; u < 4; u++) {
                    float4 b = *(const float4*)(src + u * 4);
                    B_lds[cg + u * 4 + 0][r] = b.x; B_lds[cg + u * 4 + 1][r] = b.y;
                    B_lds[cg + u * 4 + 2][r] = b.z; B_lds[cg + u * 4 + 3][r] = b.w;
                }
            }
            __syncthreads();
#pragma unroll
            for (int c = 0; c < CKG; c++) {
                float4 av = *(const float4*)&A_lds[c][ty * 4];
                float4 b0 = *(const float4*)&B_lds[c][tx * 4];
                float4 b1 = *(const float4*)&B_lds[c][tx * 4 + 64];
                float a[4]  = {av.x, av.y, av.z, av.w};
                float bb[8] = {b0.x, b0.y, b0.z, b0.w, b1.x, b1.y, b1.z, b1.w};
#pragma unroll
                for (int rr = 0; rr < 4; rr++)
#pragma unroll
                    for (int jj = 0; jj < 8; jj++)
                        acc[rr][jj] = fmaf(a[rr], bb[jj], acc[rr][jj]);
            }
        }
        // scores -> S (scalar stores; pad keeps scan conflict-free)
        float sqj0[4], sqj1[4];
#pragma unroll
        for (int jj = 0; jj < 4; jj++) {
            sqj0[jj] = sq[j0 + tx * 4 + jj];
            sqj1[jj] = sq[j0 + tx * 4 + 64 + jj];
        }
#pragma unroll
        for (int rr = 0; rr < 4; rr++) {
            int r = ty * 4 + rr;
            float sv = sqi[rr];
#pragma unroll
            for (int jj = 0; jj < 4; jj++) {
                S[r][tx * 4 + jj]      = (sv + sqj0[jj]) - 2.f * acc[rr][jj];
                S[r][tx * 4 + 64 + jj] = (sv + sqj1[jj]) - 2.f * acc[rr][4 + jj];
            }
        }
        __syncthreads();
        // per-row serial top-8 update (thread r owns row r; tie-break = lower index,
        // replicating lax.top_k stability)
        if (tid < TM) {
            int r = tid, gi = i0 + r;
            for (int j = 0; j < TN; j++) {
                int gj = j0 + j;
                if (gj == gi) continue;
                float v = S[r][j];
                float wv = topv[r][7]; int wi = topi[r][7];
                if (v < wv || (v == wv && gj < wi)) {
                    int p = 7;
                    while (p > 0) {
                        float pv = topv[r][p - 1]; int pi = topi[r][p - 1];
                        if (v < pv || (v == pv && gj < pi)) {
                            topv[r][p] = pv; topi[r][p] = pi; p--;
                        } else break;
                    }
                    topv[r][p] = v; topi[r][p] = gj;
                }
            }
        }
        __syncthreads();
    }
    if (tid < TM) {
        int gi = i0 + tid;
#pragma unroll
        for (int k = 0; k < 8; k++) {
            candv[(size_t)gi * 32 + q * 8 + k] = topv[tid][k];
            candi[(size_t)gi * 32 + q * 8 + k] = topi[tid][k];
        }
    }
}

// ------------- merge 4 quarter-lists -> knn[i][0..7] -------------
__global__ __launch_bounds__(256) void merge_topk_kernel(
        const float* __restrict__ candv, const int* __restrict__ candi,
        int* __restrict__ knn) {
    int i = blockIdx.x * 256 + threadIdx.x;
    if (i >= N_NODES) return;
    const float* cv = candv + (size_t)i * 32;
    const int*   ci = candi + (size_t)i * 32;
    unsigned used = 0;
    for (int k = 0; k < KNN; k++) {
        float bv = 3.5e38f; int bi = 0x7fffffff; int bm = 0;
        for (int m = 0; m < 32; m++) {
            if (used & (1u << m)) continue;
            float v = cv[m]; int ix = ci[m];
            if (v < bv || (v == bv && ix < bi)) { bv = v; bi = ix; bm = m; }
        }
        used |= 1u << bm;
        knn[(size_t)i * KNN + k] = bi;
    }
}

// ------------- graph build -------------
__global__ __launch_bounds__(256) void graph_init_kernel(int* deg, int* cnt) {
    int i = blockIdx.x * 256 + threadIdx.x;
    if (i < N_NODES) { deg[i] = 1; cnt[i] = 0; }   // 1 = self-loop
}
__global__ __launch_bounds__(256) void deg_count_kernel(const int* __restrict__ knn,
                                                        int* deg) {
    int e = blockIdx.x * 256 + threadIdx.x;
    if (e < N_NODES * KNN) atomicAdd(&deg[knn[e]], 1);
}
__global__ __launch_bounds__(256) void dinv_kernel(const int* __restrict__ deg,
                                                   float* __restrict__ dinv) {
    int i = blockIdx.x * 256 + threadIdx.x;
    if (i < N_NODES) dinv[i] = rsqrtf((float)deg[i]);   // deg >= 1 always
}
__global__ __launch_bounds__(256) void scan_kernel(const int* __restrict__ deg,
                                                   int* __restrict__ row_ptr) {
    __shared__ int partial[256];
    const int CHUNK = (N_NODES + 255) / 256;  // 25
    int tid = threadIdx.x;
    int start = tid * CHUNK;
    int end = start + CHUNK; if (end > N_NODES) end = N_NODES;
    int s = 0;
    for (int i = start; i < end; i++) s += deg[i];
    partial[tid] = s;
    __syncthreads();
    if (tid == 0) {
        int run = 0;
        for (int k = 0; k < 256; k++) { int v = partial[k]; partial[k] = run; run += v; }
        row_ptr[N_NODES] = run;
    }
    __syncthreads();
    int run = partial[tid];
    for (int i = start; i < end; i++) { row_ptr[i] = run; run += deg[i]; }
}
__global__ __launch_bounds__(256) void scatter_kernel(const int* __restrict__ knn,
        const int* __restrict__ row_ptr, int* cnt, int* __restrict__ col) {
    int i = blockIdx.x * 256 + threadIdx.x;
    if (i >= N_NODES) return;
    int p = row_ptr[i] + atomicAdd(&cnt[i], 1);
    col[p] = i;                                   // self-loop edge (i,i)
#pragma unroll
    for (int j = 0; j < KNN; j++) {
        int d = knn[(size_t)i * KNN + j];         // edge src=i -> dst=d
        int q = row_ptr[d] + atomicAdd(&cnt[d], 1);
        col[q] = i;
    }
}

// ------------- generic fp32 GEMM  C[M,N] = A[M,K] @ B[K,N] -------------
// M%64==0, N%128==0, K%32==0
__global__ __launch_bounds__(256) void sgemm_nn_kernel(
        const float* __restrict__ A, const float* __restrict__ B,
        float* __restrict__ C, int M, int N, int K) {
    __shared__ float A_lds[CKG][TM];
    __shared__ float B_lds[CKG][TN];
    int tid = threadIdx.x;
    int nt = N / TN;
    int it = blockIdx.x / nt, jt = blockIdx.x % nt;
    int i0 = it * TM, j0 = jt * TN;
    int ty = tid >> 4, tx = tid & 15;
    float acc[4][8];
#pragma unroll
    for (int a = 0; a < 4; a++)
#pragma unroll
        for (int b = 0; b < 8; b++) acc[a][b] = 0.f;

    for (int cc = 0; cc < K; cc += CKG) {
        __syncthreads();
        {   // A transpose-load
            int r  = tid >> 2;
            int cg = (tid & 3) * 8;
            const float* src = A + (size_t)(i0 + r) * K + cc + cg;
            float4 a0 = *(const float4*)src;
            float4 a1 = *(const float4*)(src + 4);
            A_lds[cg + 0][r] = a0.x; A_lds[cg + 1][r] = a0.y;
            A_lds[cg + 2][r] = a0.z; A_lds[cg + 3][r] = a0.w;
            A_lds[cg + 4][r] = a1.x; A_lds[cg + 5][r] = a1.y;
            A_lds[cg + 6][r] = a1.z; A_lds[cg + 7][r] = a1.w;
        }
        {   // B direct load (row-major rows of B are contiguous in N)
            int crow = tid >> 5;          // 0..7
            int j4   = (tid & 31) * 4;    // 0..124
#pragma unroll
            for (int u = 0; u < 4; u++) {
                int c = crow + u * 8;
                *(float4*)&B_lds[c][j4] =
                    *(const float4*)(B + (size_t)(cc + c) * N + j0 + j4);
            }
        }
        __syncthreads();
#pragma unroll
        for (int c = 0; c < CKG; c++) {
            float4 av = *(const float4*)&A_lds[c][ty * 4];
            float4 b0 = *(const float4*)&B_lds[c][tx * 4];
            float4 b1 = *(const float4*)&B_lds[c][tx * 4 + 64];
            float a[4]  = {av.x, av.y, av.z, av.w};
            float bb[8] = {b0.x, b0.y, b0.z, b0.w, b1.x, b1.y, b1.z, b1.w};
#pragma unroll
            for (int rr = 0; rr < 4; rr++)
#pragma unroll
                for (int jj = 0; jj < 8; jj++)
                    acc[rr][jj] = fmaf(a[rr], bb[jj], acc[rr][jj]);
        }
    }
#pragma unroll
    for (int rr = 0; rr < 4; rr++) {
        int r = i0 + ty * 4 + rr;
        float4 o0 = {acc[rr][0], acc[rr][1], acc[rr][2], acc[rr][3]};
        float4 o1 = {acc[rr][4], acc[rr][5], acc[rr][6], acc[rr][7]};
        *(float4*)(C + (size_t)r * N + j0 + tx * 4)      = o0;
        *(float4*)(C + (size_t)r * N + j0 + tx * 4 + 64) = o1;
    }
}

// ------------- GCN aggregation: out[d] = relu(dinv[d]*sum_s hw[s]*dinv[s] + b) ----
// one wave per node; grid = N_NODES/4 blocks of 256
__global__ __launch_bounds__(256) void aggregate_kernel(
        const float* __restrict__ hw, const int* __restrict__ row_ptr,
        const int* __restrict__ col, const float* __restrict__ dinv,
        const float* __restrict__ bias, float* __restrict__ out) {
    int node = blockIdx.x * 4 + (threadIdx.x >> 6);
    int lane = threadIdx.x & 63;
    int e0 = row_ptr[node], e1 = row_ptr[node + 1];
    float4 acc0 = {0.f, 0.f, 0.f, 0.f}, acc1 = {0.f, 0.f, 0.f, 0.f};
    for (int e = e0; e < e1; e++) {
        int s = col[e];
        float w = dinv[s];
        const float* hr = hw + (size_t)s * ODIM;
        float4 v0 = *(const float4*)(hr + lane * 4);
        float4 v1 = *(const float4*)(hr + 256 + lane * 4);
        acc0.x = fmaf(w, v0.x, acc0.x); acc0.y = fmaf(w, v0.y, acc0.y);
        acc0.z = fmaf(w, v0.z, acc0.z); acc0.w = fmaf(w, v0.w, acc0.w);
        acc1.x = fmaf(w, v1.x, acc1.x); acc1.y = fmaf(w, v1.y, acc1.y);
        acc1.z = fmaf(w, v1.z, acc1.z); acc1.w = fmaf(w, v1.w, acc1.w);
    }
    float wd = dinv[node];
    float4 b0 = *(const float4*)(bias + lane * 4);
    float4 b1 = *(const float4*)(bias + 256 + lane * 4);
    float4 o0, o1;
    o0.x = fmaxf(fmaf(acc0.x, wd, b0.x), 0.f);
    o0.y = fmaxf(fmaf(acc0.y, wd, b0.y), 0.f);
    o0.z = fmaxf(fmaf(acc0.z, wd, b0.z), 0.f);
    o0.w = fmaxf(fmaf(acc0.w, wd, b0.w), 0.f);
    o1.x = fmaxf(fmaf(acc1.x, wd, b1.x), 0.f);
    o1.y = fmaxf(fmaf(acc1.y, wd, b1.y), 0.f);
    o1.z = fmaxf(fmaf(acc1.z, wd, b1.z), 0.f);
    o1.w = fmaxf(fmaf(acc1.w, wd, b1.w), 0.f);
    *(float4*)(out + (size_t)node * ODIM + lane * 4)       = o0;
    *(float4*)(out + (size_t)node * ODIM + 256 + lane * 4) = o1;
}

extern "C" void kernel_launch(void* const* d_in, const int* in_sizes, int n_in,
                              void* d_out, int out_size, void* d_ws, size_t ws_size,
                              hipStream_t stream) {
    const float* x  = (const float*)d_in[0];
    const float* W1 = (const float*)d_in[1];
    const float* b1 = (const float*)d_in[2];
    const float* W2 = (const float*)d_in[3];
    const float* b2 = (const float*)d_in[4];
    float* out = (float*)d_out;
    char* ws = (char*)d_ws;

    float* sq      = (float*)(ws + SQ_OFF);
    float* candv   = (float*)(ws + CANDV_OFF);
    int*   candi   = (int*)  (ws + CANDI_OFF);
    int*   knn     = (int*)  (ws + KNN_OFF);
    int*   deg     = (int*)  (ws + DEG_OFF);
    int*   cnt     = (int*)  (ws + CNT_OFF);
    float* dinv    = (float*)(ws + DINV_OFF);
    int*   row_ptr = (int*)  (ws + RPTR_OFF);
    int*   col     = (int*)  (ws + COL_OFF);
    float* hw      = (float*)(ws + HW_OFF);
    float* h1      = (float*)(ws + H1_OFF);

    sq_kernel<<<N_NODES, 64, 0, stream>>>(x, sq);
    gram_topk_kernel<<<NPANEL * 4, 256, 0, stream>>>(x, sq, candv, candi);
    merge_topk_kernel<<<(N_NODES + 255) / 256, 256, 0, stream>>>(candv, candi, knn);
    graph_init_kernel<<<(N_NODES + 255) / 256, 256, 0, stream>>>(deg, cnt);
    deg_count_kernel<<<(N_NODES * KNN) / 256, 256, 0, stream>>>(knn, deg);
    dinv_kernel<<<(N_NODES + 255) / 256, 256, 0, stream>>>(deg, dinv);
    scan_kernel<<<1, 256, 0, stream>>>(deg, row_ptr);
    scatter_kernel<<<(N_NODES + 255) / 256, 256, 0, stream>>>(knn, row_ptr, cnt, col);

    sgemm_nn_kernel<<<NPANEL * (ODIM / TN), 256, 0, stream>>>(x,  W1, hw, N_NODES, ODIM, CDIM);
    aggregate_kernel<<<N_NODES / 4, 256, 0, stream>>>(hw, row_ptr, col, dinv, b1, h1);
    sgemm_nn_kernel<<<NPANEL * (ODIM / TN), 256, 0, stream>>>(h1, W2, hw, N_NODES, ODIM, ODIM);
    aggregate_kernel<<<N_NODES / 4, 256, 0, stream>>>(hw, row_ptr, col, dinv, b2, out);
}